// Round 8
// baseline (2565.247 us; speedup 1.0000x reference)
//
#include <hip/hip_runtime.h>
#include <math.h>
#include <stdint.h>

// Keep compiler contraction OFF globally: the ONLY fusions are my explicit
// fmaf() calls, which model LLVM's contract-FMF fusion on the XLA CPU host.
#pragma clang fp contract(off)

#define N_PIX 802816          // 16*1*224*224 = 512*1568
#define T_WIN 100
#define KN_MAX 96             // Knuth subkey chain length
#define RJ_MAX 48             // rejection subkey chain length (G ~ 9)
#define G_SLOT (KN_MAX * 2 + RJ_MAX * 4)   // ws u32 index of global max-iter
#define MRC_WS (G_SLOT + 1)   // 8 floats: make_rej(1e5) fields
#define CNT_WS (MRC_WS + 8)   // survivor count
#define OVF_WS (CNT_WS + 1)   // overflow flag
#define TAB_BASE 98000        // lgamma table covers kf in [TAB_BASE, TAB_BASE+TAB_N)
#define TAB_N    4096
#define TAB_WS   (OVF_WS + 1)
#define LIST_WS  (TAB_WS + TAB_N)
#define LIST_CAP (8u * 1024u * 1024u)
#define WS_TAB_NEEDED ((size_t)(TAB_WS + TAB_N) * 4)
#define WS_FAST_NEEDED ((size_t)(LIST_WS + LIST_CAP) * 4)
#define WBUF 640              // per-wave LDS survivor buffer (mean 450, +9 sigma)

// ---------------- threefry2x32 (JAX rotation/injection schedule) -------------
__device__ __forceinline__ void tf2x32(uint32_t k0, uint32_t k1,
                                       uint32_t x0, uint32_t x1,
                                       uint32_t &o0, uint32_t &o1) {
  uint32_t ks2 = k0 ^ k1 ^ 0x1BD11BDAu;
  x0 += k0; x1 += k1;
#define TF_R(r) { x0 += x1; x1 = (x1 << (r)) | (x1 >> (32 - (r))); x1 ^= x0; }
  TF_R(13) TF_R(15) TF_R(26) TF_R(6)
  x0 += k1;  x1 += ks2 + 1u;
  TF_R(17) TF_R(29) TF_R(16) TF_R(24)
  x0 += ks2; x1 += k0 + 2u;
  TF_R(13) TF_R(15) TF_R(26) TF_R(6)
  x0 += k0;  x1 += k1 + 3u;
  TF_R(17) TF_R(29) TF_R(16) TF_R(24)
  x0 += k1;  x1 += ks2 + 4u;
  TF_R(13) TF_R(15) TF_R(26) TF_R(6)
  x0 += ks2; x1 += k0 + 5u;
#undef TF_R
  o0 = x0; o1 = x1;
}

__device__ __forceinline__ uint32_t unif_bits(uint32_t s0, uint32_t s1, uint32_t p) {
  uint32_t a, b;
  tf2x32(s0, s1, 0u, p, a, b);
  return a ^ b;
}

__device__ __forceinline__ float bits_to_unit(uint32_t bits) {
  return __uint_as_float(0x3f800000u | (bits >> 9)) - 1.0f;
}

// ---------------- XLA CPU f32 log (verified bit-exact in round 5) ------------
__device__ __forceinline__ float xla_logf(float xin) {
#pragma clang fp contract(off)
  if (xin == 0.0f) return __uint_as_float(0xff800000u);           // -inf
  if (!(xin > 0.0f)) return __uint_as_float(0x7fc00000u);         // nan
  float x = fmaxf(xin, __uint_as_float(0x00800000u));             // flush denorm
  uint32_t ib = __float_as_uint(x);
  float e = (float)((int)(ib >> 23) - 126);
  ib = (ib & 0x007fffffu) | 0x3f000000u;                          // [0.5,1)
  x = __uint_as_float(ib);
  float tmp = 0.0f, eadj = 0.0f;
  if (x < (float)0.707106781186547524) { tmp = x; eadj = 1.0f; }
  x = x - 1.0f;
  e = e - eadj;
  x = x + tmp;
  float x2 = x * x;
  float x3 = x2 * x;
  float y  = fmaf((float)7.0376836292e-2,  x, (float)-1.1514610310e-1);
  float y1 = fmaf((float)-1.2420140846e-1, x, (float)1.4249322787e-1);
  float y2 = fmaf((float)2.0000714765e-1,  x, (float)-2.4999993993e-1);
  y  = fmaf(y,  x, (float)1.1676998740e-1);
  y1 = fmaf(y1, x, (float)-1.6668057665e-1);
  y2 = fmaf(y2, x, (float)3.3333331174e-1);
  y  = fmaf(y, x3, y1);
  y  = fmaf(y, x3, y2);
  float eq1 = e * (float)-2.12194440e-4;   // standalone mul
  y = fmaf(y, x3, eq1);                    // fadd(mul,mul): operand-0 fuses
  x = fmaf(-x2, 0.5f, x);                  // fsub(x, mul) -> fnmadd
  x = x + y;                               // add of two fma results
  x = fmaf(e, (float)0.693359375, x);      // fadd(x, mul) -> fma
  return x;
}

__device__ __forceinline__ float xla_log1pf(float w) {
#pragma clang fp contract(off)
  if (fabsf(w) < (float)1e-4) return fmaf(-0.5f, w, 1.0f) * w;
  return xla_logf(w + 1.0f);
}

__device__ __forceinline__ float xla_lgammaf_pos(float x) {
#pragma clang fp contract(off)
  const float kBase = (float)0.99999999999980993227684700473478;
  const float c0 = (float)676.520368121885098567009190444019;
  const float c1 = (float)-1259.13921672240287047156078755283;
  const float c2 = (float)771.3234287776530788486528258894;
  const float c3 = (float)-176.61502916214059906584551354;
  const float c4 = (float)12.507343278686904814458936853;
  const float c5 = (float)-0.13857109526572011689554707;
  const float c6 = (float)9.984369578019570859563e-6;
  const float c7 = (float)1.50563273514931155834e-7;
  const float kLogSqrtTwoPi = (float)0.91893853320467274178032973640562;
  const float kGPlusHalf = 7.5f;
  const float kLogGPlusHalf = (float)2.0149030205422647065; // log(7.5)
  float z = x - 1.0f;
  float sum = kBase;
  sum = sum + c0 / ((z + 0.0f) + 1.0f);
  sum = sum + c1 / ((z + 1.0f) + 1.0f);
  sum = sum + c2 / ((z + 2.0f) + 1.0f);
  sum = sum + c3 / ((z + 3.0f) + 1.0f);
  sum = sum + c4 / ((z + 4.0f) + 1.0f);
  sum = sum + c5 / ((z + 5.0f) + 1.0f);
  sum = sum + c6 / ((z + 6.0f) + 1.0f);
  sum = sum + c7 / ((z + 7.0f) + 1.0f);
  float t = kGPlusHalf + z;
  float log_t = kLogGPlusHalf + xla_log1pf(z / kGPlusHalf);
  float log_y = fmaf((z + 0.5f) - t / log_t, log_t, kLogSqrtTwoPi) + xla_logf(sum);
  return log_y;
}

// ---------------- rejection sampler shared pieces ----------------------------
struct RejConst {
  float lam, neg_lam, log_lam, aa, bb, inv_alpha, v_r, two_a;
};

__device__ __forceinline__ RejConst make_rej(float lam) {
  RejConst rc;
  rc.lam = lam;
  rc.neg_lam = -lam;
  rc.log_lam = xla_logf(lam);
  float sq = (float)sqrt((double)lam);                  // CR f32 sqrt
  rc.bb = fmaf(2.53f, sq, (float)0.931);
  rc.aa = fmaf((float)0.02483, rc.bb, (float)-0.059);
  rc.inv_alpha = (float)1.1239 + (float)1.1328 / (rc.bb - (float)3.4);
  rc.v_r = (float)0.9277 - (float)3.6224 / (rc.bb - 2.0f);
  rc.two_a = 2.0f * rc.aa;
  return rc;
}

// One rejection iteration (full lgamma) -- byte-identical to rounds 5-7.
__device__ __forceinline__ bool rej_step4(const RejConst& rc, uint4 ch,
                                          uint32_t p, float& kf_out) {
  float u = bits_to_unit(unif_bits(ch.x, ch.y, p)) - 0.5f;
  float v = bits_to_unit(unif_bits(ch.z, ch.w, p));
  float u_sh = 0.5f - fabsf(u);
  float kf = floorf(fmaf(rc.two_a / u_sh + rc.bb, u, rc.lam) + (float)0.43);
  kf_out = kf;
  if ((u_sh >= (float)0.07) && (v <= rc.v_r)) return true;          // accept1
  if ((kf < 0.0f) || ((u_sh < (float)0.013) && (v > u_sh))) return false; // reject
  float sv = xla_logf((v * rc.inv_alpha) / ((rc.aa / (u_sh * u_sh)) + rc.bb));
  float tv = fmaf(kf, rc.log_lam, rc.neg_lam) - xla_lgammaf_pos(kf + 1.0f);
  return sv <= tv;                                                  // accept2
}

// Table-assisted variant (identical bits: table holds xla_lgammaf_pos values).
__device__ __forceinline__ bool rej_step_tab(const RejConst& rc, uint4 ch,
                                             uint32_t p, const float* lgtab,
                                             float& kf_out) {
  float u = bits_to_unit(unif_bits(ch.x, ch.y, p)) - 0.5f;
  float v = bits_to_unit(unif_bits(ch.z, ch.w, p));
  float u_sh = 0.5f - fabsf(u);
  float kf = floorf(fmaf(rc.two_a / u_sh + rc.bb, u, rc.lam) + (float)0.43);
  kf_out = kf;
  if ((u_sh >= (float)0.07) && (v <= rc.v_r)) return true;          // accept1
  if ((kf < 0.0f) || ((u_sh < (float)0.013) && (v > u_sh))) return false; // reject
  float sv = xla_logf((v * rc.inv_alpha) / ((rc.aa / (u_sh * u_sh)) + rc.bb));
  int ki = (int)kf - TAB_BASE;
  float lg = (ki >= 0 && ki < TAB_N) ? lgtab[ki] : xla_lgammaf_pos(kf + 1.0f);
  float tv = fmaf(kf, rc.log_lam, rc.neg_lam) - lg;
  return sv <= tv;                                                  // accept2
}

// ---------------- prologue: subkey chains + mrc + lgamma table ---------------
__global__ void chain_init(uint32_t* __restrict__ ws, int build_table, int fast) {
  if (blockIdx.x == 0) {
    if (threadIdx.x != 0) return;
    ws[G_SLOT] = 1u;                       // G >= 1 always
    if (fast) { ws[CNT_WS] = 0u; ws[OVF_WS] = 0u; }
    uint32_t r0 = 0u, r1 = 42u;            // jax.random.key(42) -> (0,42)
    for (int j = 0; j < KN_MAX; ++j) {
      uint32_t s0, s1, n0, n1;
      tf2x32(r0, r1, 0u, 1u, s0, s1);
      tf2x32(r0, r1, 0u, 0u, n0, n1);
      ws[2 * j] = s0; ws[2 * j + 1] = s1;
      r0 = n0; r1 = n1;
    }
  } else if (blockIdx.x == 1) {
    if (threadIdx.x == 0) {
      uint32_t c0 = 0u, c1 = 42u;
      for (int j = 0; j < RJ_MAX; ++j) {
        uint32_t a0, a1, b0, b1, n0, n1;
        tf2x32(c0, c1, 0u, 1u, a0, a1);
        tf2x32(c0, c1, 0u, 2u, b0, b1);
        tf2x32(c0, c1, 0u, 0u, n0, n1);
        uint32_t base = KN_MAX * 2 + 4 * j;
        ws[base + 0] = a0; ws[base + 1] = a1; ws[base + 2] = b0; ws[base + 3] = b1;
        c0 = n0; c1 = n1;
      }
    } else if (threadIdx.x == 64 && fast) {
      RejConst m = make_rej(100000.0f);
      ws[MRC_WS + 0] = __float_as_uint(m.lam);
      ws[MRC_WS + 1] = __float_as_uint(m.neg_lam);
      ws[MRC_WS + 2] = __float_as_uint(m.log_lam);
      ws[MRC_WS + 3] = __float_as_uint(m.aa);
      ws[MRC_WS + 4] = __float_as_uint(m.bb);
      ws[MRC_WS + 5] = __float_as_uint(m.inv_alpha);
      ws[MRC_WS + 6] = __float_as_uint(m.v_r);
      ws[MRC_WS + 7] = __float_as_uint(m.two_a);
    }
  } else if (build_table) {
    int i = (blockIdx.x - 2) * 256 + threadIdx.x;   // 16 blocks x 256 = TAB_N
    if (i < TAB_N) {
      float kf = (float)(TAB_BASE + i);             // exact (< 2^24)
      ws[TAB_WS + i] = __float_as_uint(xla_lgammaf_pos(kf + 1.0f));
    }
  }
}

__device__ __forceinline__ RejConst load_mrc(const float* mrcsh) {
  RejConst rc;
  rc.lam = mrcsh[0]; rc.neg_lam = mrcsh[1]; rc.log_lam = mrcsh[2];
  rc.aa = mrcsh[3];  rc.bb = mrcsh[4];      rc.inv_alpha = mrcsh[5];
  rc.v_r = mrcsh[6]; rc.two_a = mrcsh[7];
  return rc;
}

// ---------------- pass 0: evaluate chain index j=0 for ALL (t,n) -------------
// One lane per pixel (block-compacted by class), t-loop inside. Uniform j=0
// keys (SGPR). Rejecting positions appended to global survivor list via
// per-wave LDS buffers (1 atomicAdd per flush).
__global__ void __launch_bounds__(512)
rej_pass0(const float* __restrict__ img, uint32_t* __restrict__ ws) {
  __shared__ float lgtab[TAB_N];
  __shared__ float mrcsh[8];
  __shared__ int waveRej[8];
  __shared__ unsigned short order[512];
  __shared__ uint32_t wbuf[8][WBUF];

  const int tid = threadIdx.x;
  for (int i = tid; i < TAB_N; i += 512) lgtab[i] = __uint_as_float(ws[TAB_WS + i]);
  if (tid < 8) mrcsh[tid] = __uint_as_float(ws[MRC_WS + tid]);

  // classify + deterministic compaction (round-7 pattern)
  int n0 = blockIdx.x * 512 + tid;
  float uimg0 = img[n0];
  bool isRej = (uimg0 != 0.0f) && !((1.0f / uimg0) < 10.0f);
  int lane = tid & 63, w = tid >> 6;
  unsigned long long bal = __ballot(isRej ? 1 : 0);
  int within = (int)__popcll(bal & ((1ull << lane) - 1ull));
  if (lane == 0) waveRej[w] = (int)__popcll(bal);
  __syncthreads();
  int rejBefore = 0, totalRej = 0;
  for (int i = 0; i < 8; ++i) { int c = waveRej[i]; totalRej += c; if (i < w) rejBefore += c; }
  int nMasked = 512 - totalRej;
  int slot = isRej ? (nMasked + rejBefore + within)
                   : (64 * w - rejBefore) + (lane - within);
  order[slot] = (unsigned short)tid;
  __syncthreads();

  int n = blockIdx.x * 512 + (int)order[tid];
  bool myRej = (tid >= nMasked);
  RejConst rc;
  if (myRej) rc = make_rej(1.0f / img[n]);
  else       rc = load_mrc(mrcsh);

  uint4 ch0 = make_uint4(ws[KN_MAX * 2 + 0], ws[KN_MAX * 2 + 1],
                         ws[KN_MAX * 2 + 2], ws[KN_MAX * 2 + 3]);  // uniform
  uint32_t* cnt  = ws + CNT_WS;
  uint32_t* list = ws + LIST_WS;
  uint32_t wcnt = 0;   // per-wave survivor count (identical in all lanes)
  uint32_t p = (uint32_t)n;

  for (int t = 0; t < T_WIN; ++t, p += N_PIX) {
    float kf;
    bool acc = rej_step_tab(rc, ch0, p, lgtab, kf);
    unsigned long long mask = __ballot(acc ? 0 : 1);
    if (mask) {
      uint32_t rank = (uint32_t)__popcll(mask & ((1ull << lane) - 1ull));
      if (!acc) wbuf[w][wcnt + rank] = p;
      wcnt += (uint32_t)__popcll(mask);
    }
    if (wcnt >= WBUF - 64) {  // flush (expected never mid-loop)
      uint32_t base = 0;
      if (lane == 0) base = atomicAdd(cnt, wcnt);
      base = (uint32_t)__shfl((int)base, 0, 64);
      for (uint32_t i = (uint32_t)lane; i < wcnt; i += 64) {
        uint32_t idx = base + i;
        if (idx < LIST_CAP) list[idx] = wbuf[w][i];
        else atomicOr(ws + OVF_WS, 1u);
      }
      wcnt = 0;
    }
  }
  if (wcnt > 0) {
    uint32_t base = 0;
    if (lane == 0) base = atomicAdd(cnt, wcnt);
    base = (uint32_t)__shfl((int)base, 0, 64);
    for (uint32_t i = (uint32_t)lane; i < wcnt; i += 64) {
      uint32_t idx = base + i;
      if (idx < LIST_CAP) list[idx] = wbuf[w][i];
      else atomicOr(ws + OVF_WS, 1u);
    }
  }
}

// ---------------- finish: survivors to first-accept (j>=1), max -> G ---------
__global__ void __launch_bounds__(256)
rej_finish(const float* __restrict__ img, uint32_t* __restrict__ ws,
           uint32_t* __restrict__ gmax) {
  __shared__ uint4 rj4[RJ_MAX];
  __shared__ float lgtab[TAB_N];
  __shared__ float mrcsh[8];
  __shared__ uint32_t red[256];
  const int tid = threadIdx.x;
  for (int i = tid; i < RJ_MAX; i += 256) {
    uint32_t b = KN_MAX * 2 + 4 * i;
    rj4[i] = make_uint4(ws[b], ws[b + 1], ws[b + 2], ws[b + 3]);
  }
  for (int i = tid; i < TAB_N; i += 256) lgtab[i] = __uint_as_float(ws[TAB_WS + i]);
  if (tid < 8) mrcsh[tid] = __uint_as_float(ws[MRC_WS + tid]);
  __syncthreads();

  uint32_t cnt = ws[CNT_WS];
  if (cnt > LIST_CAP) cnt = LIST_CAP;
  uint32_t mymax = 1;
  for (uint32_t i = blockIdx.x * 256 + tid; i < cnt; i += gridDim.x * 256) {
    uint32_t p = ws[LIST_WS + i];
    uint32_t n = p % (uint32_t)N_PIX;
    float uimg = img[n];
    bool isRej = (uimg != 0.0f) && !((1.0f / uimg) < 10.0f);
    RejConst rc;
    if (isRej) rc = make_rej(1.0f / uimg);
    else       rc = load_mrc(mrcsh);
    uint32_t fa = RJ_MAX;
    for (int j = 1; j < RJ_MAX; ++j) {
      float kf;
      if (rej_step_tab(rc, rj4[j], p, lgtab, kf)) { fa = (uint32_t)(j + 1); break; }
    }
    if (fa > mymax) mymax = fa;
  }
  red[tid] = mymax;
  __syncthreads();
  for (int s2 = 128; s2 > 0; s2 >>= 1) {
    if (tid < s2) {
      uint32_t o = red[tid + s2];
      if (o > red[tid]) red[tid] = o;
    }
    __syncthreads();
  }
  if (tid == 0) atomicMax((unsigned int*)gmax, red[0]);
}

// ---------------- fallback / overflow guard: full first-accept scan ----------
__global__ void __launch_bounds__(512)
rej_gmax_full(const float* __restrict__ img, const uint32_t* __restrict__ ws,
              uint32_t* __restrict__ gmax, int use_table, int skip_unless_ovf) {
  if (skip_unless_ovf && ws[OVF_WS] == 0u) return;
  __shared__ uint4 rj4[RJ_MAX];
  __shared__ float lgtab[TAB_N];
  __shared__ int waveRej[8];
  __shared__ unsigned short order[512];
  __shared__ uint32_t red[512];

  const int tid = threadIdx.x;
  for (int i = tid; i < RJ_MAX; i += 512) {
    uint32_t b = KN_MAX * 2 + 4 * i;
    rj4[i] = make_uint4(ws[b], ws[b + 1], ws[b + 2], ws[b + 3]);
  }
  if (use_table)
    for (int i = tid; i < TAB_N; i += 512) lgtab[i] = __uint_as_float(ws[TAB_WS + i]);

  int n0 = blockIdx.x * 512 + tid;
  float uimg0 = img[n0];
  bool isRej = (uimg0 != 0.0f) && !((1.0f / uimg0) < 10.0f);
  int lane = tid & 63, w = tid >> 6;
  unsigned long long bal = __ballot(isRej ? 1 : 0);
  int within = (int)__popcll(bal & ((1ull << lane) - 1ull));
  if (lane == 0) waveRej[w] = (int)__popcll(bal);
  __syncthreads();
  int rejBefore = 0, totalRej = 0;
  for (int i = 0; i < 8; ++i) { int c = waveRej[i]; totalRej += c; if (i < w) rejBefore += c; }
  int nMasked = 512 - totalRej;
  int slot = isRej ? (nMasked + rejBefore + within)
                   : (64 * w - rejBefore) + (lane - within);
  order[slot] = (unsigned short)tid;
  __syncthreads();

  int n = blockIdx.x * 512 + (int)order[tid];
  bool myRej = (tid >= nMasked);
  RejConst rc = make_rej(myRej ? (1.0f / img[n]) : 100000.0f);

  uint32_t mymax = 1;
  {
    uint32_t p = (uint32_t)n;
    int t = 0, j = 0;
    while (t < T_WIN) {
      float kf;
      bool acc;
      if (use_table) acc = rej_step_tab(rc, rj4[j], p, lgtab, kf);
      else           acc = rej_step4(rc, rj4[j], p, kf);
      if (acc) {
        uint32_t fa = (uint32_t)(j + 1);
        if (fa > mymax) mymax = fa;
        ++t; p += N_PIX; j = 0;
      } else if (++j >= RJ_MAX) {
        mymax = RJ_MAX;
        ++t; p += N_PIX; j = 0;
      }
    }
  }
  red[tid] = mymax;
  __syncthreads();
  for (int s2 = 256; s2 > 0; s2 >>= 1) {
    if (tid < s2) {
      uint32_t o = red[tid + s2];
      if (o > red[tid]) red[tid] = o;
    }
    __syncthreads();
  }
  if (tid == 0) atomicMax((unsigned int*)gmax, red[0]);
}

// ---------------- pass 2: one thread per pixel, compacted + flattened --------
__global__ void __launch_bounds__(512)
spike_main(const float* __restrict__ img, int* __restrict__ out,
           const uint32_t* __restrict__ chains) {
  __shared__ uint2 kn2[KN_MAX];
  __shared__ uint4 rj4[RJ_MAX];
  __shared__ int waveRej[8];
  __shared__ unsigned short order[512];
  __shared__ int shG;
  __shared__ ulonglong2 bmsh[512];

  const int tid = threadIdx.x;
  for (int i = tid; i < KN_MAX; i += 512)
    kn2[i] = make_uint2(chains[2 * i], chains[2 * i + 1]);
  for (int i = tid; i < RJ_MAX; i += 512) {
    uint32_t b = KN_MAX * 2 + 4 * i;
    rj4[i] = make_uint4(chains[b], chains[b + 1], chains[b + 2], chains[b + 3]);
  }
  if (tid == 0) shG = (int)chains[G_SLOT];

  int n0 = blockIdx.x * 512 + tid;
  float uimg0 = img[n0];
  bool isRej = (uimg0 != 0.0f) && !((1.0f / uimg0) < 10.0f);
  int lane = tid & 63, w = tid >> 6;
  unsigned long long bal = __ballot(isRej ? 1 : 0);
  int within = (int)__popcll(bal & ((1ull << lane) - 1ull));
  if (lane == 0) waveRej[w] = (int)__popcll(bal);
  __syncthreads();
  int rejBefore = 0, totalRej = 0;
  for (int i = 0; i < 8; ++i) { int c = waveRej[i]; totalRej += c; if (i < w) rejBefore += c; }
  int nMasked = 512 - totalRej;
  int slot = isRej ? (nMasked + rejBefore + within)
                   : (64 * w - rejBefore) + (lane - within);
  order[slot] = (unsigned short)tid;
  __syncthreads();

  const int G = shG;
  int nl = (int)order[tid];
  int n = blockIdx.x * 512 + nl;
  bool myRej = (tid >= nMasked);
  float uimg = img[n];
  unsigned long long bm0 = 0ull, bm1 = 0ull;  // spike bitmap: bit (s-1), s in [1,100]

  if (myRej) {
    // Rejection: last accept in [0,G) == first accept scanning DOWN
    RejConst rc = make_rej(1.0f / uimg);
    uint32_t p = (uint32_t)n;
    int s = 0, j = G - 1, t = 0;
    while (t < T_WIN) {
      float kf;
      bool acc = rej_step4(rc, rj4[j], p, kf);
      if (acc) {
        int iv = (kf >= 102.0f) ? 102 : (int)kf;  // values >100 all dead
        if (iv == 0) iv = 1;
        s += iv;
        if (s > T_WIN) break;
        if (s <= 64) bm0 |= 1ull << (s - 1); else bm1 |= 1ull << (s - 65);
        ++t; p += N_PIX; j = G - 1;
      } else if (--j < 0) {
        break;  // impossible: G covers every position's first accept
      }
    }
  } else if (uimg != 0.0f) {
    // Knuth, flattened: one draw per step, per-lane (t,j,k,lp,s)
    float lam = 1.0f / uimg;
    float neg_lam = -lam;
    uint32_t p = (uint32_t)n;
    int s = 0, k = 0, j = 0;
    float lp = 0.0f;
    while (true) {
      uint2 sk = kn2[j];
      float u = bits_to_unit(unif_bits(sk.x, sk.y, p));
      ++k; ++j;
      lp = lp + xla_logf(u);
      if (lp <= neg_lam || j >= KN_MAX) {   // this t resolved
        int iv = k - 1;
        if (iv == 0) iv = 1;                // nz & interval==0 -> 1
        s += iv;
        if (s > T_WIN) break;               // integer cumsum <=100 exact
        if (s <= 64) bm0 |= 1ull << (s - 1); else bm1 |= 1ull << (s - 65);
        p += N_PIX; j = 0; k = 0; lp = 0.0f;
        if (p >= (uint32_t)T_WIN * (uint32_t)N_PIX) break;
      }
    }
  }

  // Stage bitmaps in LDS, write columns in ORIGINAL pixel order (coalesced).
  ulonglong2 bm; bm.x = bm0; bm.y = bm1;
  bmsh[nl] = bm;
  __syncthreads();
  ulonglong2 b2 = bmsh[tid];
  size_t base = (size_t)(blockIdx.x * 512 + tid);
  for (int t = 0; t < 64; ++t)
    out[base + (size_t)t * N_PIX] = (int)((b2.x >> t) & 1ull);
  for (int t = 64; t < T_WIN; ++t)
    out[base + (size_t)t * N_PIX] = (int)((b2.y >> (t - 64)) & 1ull);
}

extern "C" void kernel_launch(void* const* d_in, const int* in_sizes, int n_in,
                              void* d_out, int out_size, void* d_ws, size_t ws_size,
                              hipStream_t stream) {
  const float* img = (const float*)d_in[0];
  int* out = (int*)d_out;
  uint32_t* ws = (uint32_t*)d_ws;
  int use_table = (ws_size >= WS_TAB_NEEDED) ? 1 : 0;
  int use_fast  = (use_table && ws_size >= WS_FAST_NEEDED) ? 1 : 0;

  hipLaunchKernelGGL(chain_init, dim3(2 + TAB_N / 256), dim3(256), 0, stream,
                     ws, use_table, use_fast);
  if (use_fast) {
    hipLaunchKernelGGL(rej_pass0, dim3(N_PIX / 512), dim3(512), 0, stream, img, ws);
    hipLaunchKernelGGL(rej_finish, dim3(512), dim3(256), 0, stream,
                       img, ws, ws + G_SLOT);
  }
  // Fallback: full scan if no workspace for lists, or (never) list overflow.
  hipLaunchKernelGGL(rej_gmax_full, dim3(N_PIX / 512), dim3(512), 0, stream,
                     img, ws, ws + G_SLOT, use_table, use_fast);
  hipLaunchKernelGGL(spike_main, dim3(N_PIX / 512), dim3(512), 0, stream,
                     img, out, ws);
}

// Round 9
// 1797.878 us; speedup vs baseline: 1.4268x; 1.4268x over previous
//
#include <hip/hip_runtime.h>
#include <math.h>
#include <stdint.h>

// Keep compiler contraction OFF globally: the ONLY fusions are my explicit
// fmaf() calls, which model LLVM's contract-FMF fusion on the XLA CPU host.
#pragma clang fp contract(off)

#define N_PIX 802816          // 16*1*224*224 = 512*1568
#define T_WIN 100
#define KN_MAX 96             // Knuth subkey chain length
#define RJ_MAX 48             // rejection subkey chain length (G ~ 10)
#define N_WAVES (N_PIX / 64)  // 12544
#define N_WORDS (N_WAVES * T_WIN)  // 1254400 bitmap words

#define G_SLOT 384            // = KN_MAX*2 + RJ_MAX*4
#define MRC_WS  385           // 8 floats: make_rej(1e5) fields
#define CNT_WS  393           // rejection-pixel list count
#define TAB_WS  394
#define TAB_BASE 98000
#define TAB_N    4096
#define LIST_WS (TAB_WS + TAB_N)          // cap N_PIX entries -> no overflow
#define BM_WS   (LIST_WS + N_PIX)         // even -> 8B aligned
#define WS_TAB_NEEDED ((size_t)(TAB_WS + TAB_N) * 4)
#define WS_FAST_NEEDED ((size_t)(BM_WS + 2 * N_WORDS) * 4)   // ~13.3 MB

// ---------------- threefry2x32 (JAX rotation/injection schedule) -------------
__device__ __forceinline__ void tf2x32(uint32_t k0, uint32_t k1,
                                       uint32_t x0, uint32_t x1,
                                       uint32_t &o0, uint32_t &o1) {
  uint32_t ks2 = k0 ^ k1 ^ 0x1BD11BDAu;
  x0 += k0; x1 += k1;
#define TF_R(r) { x0 += x1; x1 = (x1 << (r)) | (x1 >> (32 - (r))); x1 ^= x0; }
  TF_R(13) TF_R(15) TF_R(26) TF_R(6)
  x0 += k1;  x1 += ks2 + 1u;
  TF_R(17) TF_R(29) TF_R(16) TF_R(24)
  x0 += ks2; x1 += k0 + 2u;
  TF_R(13) TF_R(15) TF_R(26) TF_R(6)
  x0 += k0;  x1 += k1 + 3u;
  TF_R(17) TF_R(29) TF_R(16) TF_R(24)
  x0 += k1;  x1 += ks2 + 4u;
  TF_R(13) TF_R(15) TF_R(26) TF_R(6)
  x0 += ks2; x1 += k0 + 5u;
#undef TF_R
  o0 = x0; o1 = x1;
}

__device__ __forceinline__ uint32_t unif_bits(uint32_t s0, uint32_t s1, uint32_t p) {
  uint32_t a, b;
  tf2x32(s0, s1, 0u, p, a, b);
  return a ^ b;
}

__device__ __forceinline__ float bits_to_unit(uint32_t bits) {
  return __uint_as_float(0x3f800000u | (bits >> 9)) - 1.0f;
}

// ---------------- XLA CPU f32 log (verified bit-exact in round 5) ------------
__device__ __forceinline__ float xla_logf(float xin) {
#pragma clang fp contract(off)
  if (xin == 0.0f) return __uint_as_float(0xff800000u);           // -inf
  if (!(xin > 0.0f)) return __uint_as_float(0x7fc00000u);         // nan
  float x = fmaxf(xin, __uint_as_float(0x00800000u));             // flush denorm
  uint32_t ib = __float_as_uint(x);
  float e = (float)((int)(ib >> 23) - 126);
  ib = (ib & 0x007fffffu) | 0x3f000000u;                          // [0.5,1)
  x = __uint_as_float(ib);
  float tmp = 0.0f, eadj = 0.0f;
  if (x < (float)0.707106781186547524) { tmp = x; eadj = 1.0f; }
  x = x - 1.0f;
  e = e - eadj;
  x = x + tmp;
  float x2 = x * x;
  float x3 = x2 * x;
  float y  = fmaf((float)7.0376836292e-2,  x, (float)-1.1514610310e-1);
  float y1 = fmaf((float)-1.2420140846e-1, x, (float)1.4249322787e-1);
  float y2 = fmaf((float)2.0000714765e-1,  x, (float)-2.4999993993e-1);
  y  = fmaf(y,  x, (float)1.1676998740e-1);
  y1 = fmaf(y1, x, (float)-1.6668057665e-1);
  y2 = fmaf(y2, x, (float)3.3333331174e-1);
  y  = fmaf(y, x3, y1);
  y  = fmaf(y, x3, y2);
  float eq1 = e * (float)-2.12194440e-4;   // standalone mul
  y = fmaf(y, x3, eq1);                    // fadd(mul,mul): operand-0 fuses
  x = fmaf(-x2, 0.5f, x);                  // fsub(x, mul) -> fnmadd
  x = x + y;                               // add of two fma results
  x = fmaf(e, (float)0.693359375, x);      // fadd(x, mul) -> fma
  return x;
}

__device__ __forceinline__ float xla_log1pf(float w) {
#pragma clang fp contract(off)
  if (fabsf(w) < (float)1e-4) return fmaf(-0.5f, w, 1.0f) * w;
  return xla_logf(w + 1.0f);
}

__device__ __forceinline__ float xla_lgammaf_pos(float x) {
#pragma clang fp contract(off)
  const float kBase = (float)0.99999999999980993227684700473478;
  const float c0 = (float)676.520368121885098567009190444019;
  const float c1 = (float)-1259.13921672240287047156078755283;
  const float c2 = (float)771.3234287776530788486528258894;
  const float c3 = (float)-176.61502916214059906584551354;
  const float c4 = (float)12.507343278686904814458936853;
  const float c5 = (float)-0.13857109526572011689554707;
  const float c6 = (float)9.984369578019570859563e-6;
  const float c7 = (float)1.50563273514931155834e-7;
  const float kLogSqrtTwoPi = (float)0.91893853320467274178032973640562;
  const float kGPlusHalf = 7.5f;
  const float kLogGPlusHalf = (float)2.0149030205422647065; // log(7.5)
  float z = x - 1.0f;
  float sum = kBase;
  sum = sum + c0 / ((z + 0.0f) + 1.0f);
  sum = sum + c1 / ((z + 1.0f) + 1.0f);
  sum = sum + c2 / ((z + 2.0f) + 1.0f);
  sum = sum + c3 / ((z + 3.0f) + 1.0f);
  sum = sum + c4 / ((z + 4.0f) + 1.0f);
  sum = sum + c5 / ((z + 5.0f) + 1.0f);
  sum = sum + c6 / ((z + 6.0f) + 1.0f);
  sum = sum + c7 / ((z + 7.0f) + 1.0f);
  float t = kGPlusHalf + z;
  float log_t = kLogGPlusHalf + xla_log1pf(z / kGPlusHalf);
  float log_y = fmaf((z + 0.5f) - t / log_t, log_t, kLogSqrtTwoPi) + xla_logf(sum);
  return log_y;
}

// ---------------- rejection sampler shared pieces ----------------------------
struct RejConst {
  float lam, neg_lam, log_lam, aa, bb, inv_alpha, v_r, two_a;
};

__device__ __forceinline__ RejConst make_rej(float lam) {
  RejConst rc;
  rc.lam = lam;
  rc.neg_lam = -lam;
  rc.log_lam = xla_logf(lam);
  float sq = (float)sqrt((double)lam);                  // CR f32 sqrt
  rc.bb = fmaf(2.53f, sq, (float)0.931);
  rc.aa = fmaf((float)0.02483, rc.bb, (float)-0.059);
  rc.inv_alpha = (float)1.1239 + (float)1.1328 / (rc.bb - (float)3.4);
  rc.v_r = (float)0.9277 - (float)3.6224 / (rc.bb - 2.0f);
  rc.two_a = 2.0f * rc.aa;
  return rc;
}

// One rejection iteration (full lgamma) -- byte-identical to rounds 5-7.
__device__ __forceinline__ bool rej_step4(const RejConst& rc, uint4 ch,
                                          uint32_t p, float& kf_out) {
  float u = bits_to_unit(unif_bits(ch.x, ch.y, p)) - 0.5f;
  float v = bits_to_unit(unif_bits(ch.z, ch.w, p));
  float u_sh = 0.5f - fabsf(u);
  float kf = floorf(fmaf(rc.two_a / u_sh + rc.bb, u, rc.lam) + (float)0.43);
  kf_out = kf;
  if ((u_sh >= (float)0.07) && (v <= rc.v_r)) return true;          // accept1
  if ((kf < 0.0f) || ((u_sh < (float)0.013) && (v > u_sh))) return false; // reject
  float sv = xla_logf((v * rc.inv_alpha) / ((rc.aa / (u_sh * u_sh)) + rc.bb));
  float tv = fmaf(kf, rc.log_lam, rc.neg_lam) - xla_lgammaf_pos(kf + 1.0f);
  return sv <= tv;                                                  // accept2
}

// Table-assisted variant (table holds xla_lgammaf_pos(kf+1): pure fn of kf,
// so valid for ANY lambda; out-of-range falls back to the full function).
__device__ __forceinline__ bool rej_step_tab(const RejConst& rc, uint4 ch,
                                             uint32_t p, const float* lgtab,
                                             float& kf_out) {
  float u = bits_to_unit(unif_bits(ch.x, ch.y, p)) - 0.5f;
  float v = bits_to_unit(unif_bits(ch.z, ch.w, p));
  float u_sh = 0.5f - fabsf(u);
  float kf = floorf(fmaf(rc.two_a / u_sh + rc.bb, u, rc.lam) + (float)0.43);
  kf_out = kf;
  if ((u_sh >= (float)0.07) && (v <= rc.v_r)) return true;          // accept1
  if ((kf < 0.0f) || ((u_sh < (float)0.013) && (v > u_sh))) return false; // reject
  float sv = xla_logf((v * rc.inv_alpha) / ((rc.aa / (u_sh * u_sh)) + rc.bb));
  int ki = (int)kf - TAB_BASE;
  float lg = (ki >= 0 && ki < TAB_N) ? lgtab[ki] : xla_lgammaf_pos(kf + 1.0f);
  float tv = fmaf(kf, rc.log_lam, rc.neg_lam) - lg;
  return sv <= tv;                                                  // accept2
}

__device__ __forceinline__ RejConst load_mrc(const uint32_t* __restrict__ ws) {
  RejConst rc;
  rc.lam       = __uint_as_float(ws[MRC_WS + 0]);
  rc.neg_lam   = __uint_as_float(ws[MRC_WS + 1]);
  rc.log_lam   = __uint_as_float(ws[MRC_WS + 2]);
  rc.aa        = __uint_as_float(ws[MRC_WS + 3]);
  rc.bb        = __uint_as_float(ws[MRC_WS + 4]);
  rc.inv_alpha = __uint_as_float(ws[MRC_WS + 5]);
  rc.v_r       = __uint_as_float(ws[MRC_WS + 6]);
  rc.two_a     = __uint_as_float(ws[MRC_WS + 7]);
  return rc;
}

// ---------------- prologue: chains + mrc + lgamma table ----------------------
__global__ void chain_init(uint32_t* __restrict__ ws, int build_table, int fast) {
  if (blockIdx.x == 0) {
    if (threadIdx.x != 0) return;
    ws[G_SLOT] = 1u;                       // G >= 1 always
    if (fast) ws[CNT_WS] = 0u;
    uint32_t r0 = 0u, r1 = 42u;            // jax.random.key(42) -> (0,42)
    for (int j = 0; j < KN_MAX; ++j) {
      uint32_t s0, s1, n0, n1;
      tf2x32(r0, r1, 0u, 1u, s0, s1);
      tf2x32(r0, r1, 0u, 0u, n0, n1);
      ws[2 * j] = s0; ws[2 * j + 1] = s1;
      r0 = n0; r1 = n1;
    }
  } else if (blockIdx.x == 1) {
    if (threadIdx.x == 0) {
      uint32_t c0 = 0u, c1 = 42u;
      for (int j = 0; j < RJ_MAX; ++j) {
        uint32_t a0, a1, b0, b1, n0, n1;
        tf2x32(c0, c1, 0u, 1u, a0, a1);
        tf2x32(c0, c1, 0u, 2u, b0, b1);
        tf2x32(c0, c1, 0u, 0u, n0, n1);
        uint32_t base = KN_MAX * 2 + 4 * j;
        ws[base + 0] = a0; ws[base + 1] = a1; ws[base + 2] = b0; ws[base + 3] = b1;
        c0 = n0; c1 = n1;
      }
    } else if (threadIdx.x == 64) {
      RejConst m = make_rej(100000.0f);
      ws[MRC_WS + 0] = __float_as_uint(m.lam);
      ws[MRC_WS + 1] = __float_as_uint(m.neg_lam);
      ws[MRC_WS + 2] = __float_as_uint(m.log_lam);
      ws[MRC_WS + 3] = __float_as_uint(m.aa);
      ws[MRC_WS + 4] = __float_as_uint(m.bb);
      ws[MRC_WS + 5] = __float_as_uint(m.inv_alpha);
      ws[MRC_WS + 6] = __float_as_uint(m.v_r);
      ws[MRC_WS + 7] = __float_as_uint(m.two_a);
    }
  } else if (build_table) {
    int i = (blockIdx.x - 2) * 256 + threadIdx.x;   // 16 blocks x 256 = TAB_N
    if (i < TAB_N) {
      float kf = (float)(TAB_BASE + i);             // exact (< 2^24)
      ws[TAB_WS + i] = __float_as_uint(xla_lgammaf_pos(kf + 1.0f));
    }
  }
}

// ---------------- pass 0 (masked): uniform j=0 eval for ALL pixels -----------
// One lane per pixel, t-loop inside, SGPR-uniform keys + mrc constants.
// Survivor ballot (masked-class only) -> bitmap word per wave per t.
// Rejection-class pixels appended to global list (handled by pass0R).
__global__ void __launch_bounds__(256)
pass0_masked(const float* __restrict__ img, uint32_t* __restrict__ ws) {
  __shared__ float lgtab[TAB_N];
  for (int i = threadIdx.x; i < TAB_N; i += 256)
    lgtab[i] = __uint_as_float(ws[TAB_WS + i]);
  __syncthreads();

  const int tid = threadIdx.x;
  const int lane = tid & 63, w = tid >> 6;
  int n = blockIdx.x * 256 + tid;
  float uimg = img[n];
  bool isRej = (uimg != 0.0f) && !((1.0f / uimg) < 10.0f);

  // append rejection-class pixels to list (wave-aggregated, order-free)
  {
    unsigned long long bal = __ballot(isRej ? 1 : 0);
    if (bal) {
      uint32_t cntw = (uint32_t)__popcll(bal);
      uint32_t base = 0;
      if (lane == 0) base = atomicAdd(ws + CNT_WS, cntw);
      base = (uint32_t)__shfl((int)base, 0, 64);
      if (isRej) {
        uint32_t rank = (uint32_t)__popcll(bal & ((1ull << lane) - 1ull));
        ws[LIST_WS + base + rank] = (uint32_t)n;
      }
    }
  }

  RejConst rc = load_mrc(ws);                       // uniform constants
  uint4 ch0 = make_uint4(ws[KN_MAX * 2 + 0], ws[KN_MAX * 2 + 1],
                         ws[KN_MAX * 2 + 2], ws[KN_MAX * 2 + 3]);
  unsigned long long* bm = (unsigned long long*)(ws + BM_WS);
  const uint32_t waveGlobal = (uint32_t)(blockIdx.x * 4 + w);
  uint32_t p = (uint32_t)n;
  for (int t = 0; t < T_WIN; ++t, p += N_PIX) {
    float kf;
    bool acc = rej_step_tab(rc, ch0, p, lgtab, kf);
    unsigned long long mask = __ballot((!acc && !isRej) ? 1 : 0);
    if (lane == 0) bm[waveGlobal * T_WIN + t] = mask;
  }
}

// ---------------- pass 0R: rejection-class pixels, dense automaton -----------
__global__ void __launch_bounds__(256)
pass0R(const float* __restrict__ img, uint32_t* __restrict__ ws,
       uint32_t* __restrict__ gmax) {
  __shared__ uint4 rj4[RJ_MAX];
  __shared__ float lgtab[TAB_N];
  for (int i = threadIdx.x; i < RJ_MAX; i += 256) {
    uint32_t b = KN_MAX * 2 + 4 * i;
    rj4[i] = make_uint4(ws[b], ws[b + 1], ws[b + 2], ws[b + 3]);
  }
  for (int i = threadIdx.x; i < TAB_N; i += 256)
    lgtab[i] = __uint_as_float(ws[TAB_WS + i]);
  __syncthreads();

  uint32_t cnt = ws[CNT_WS];
  uint32_t mymax = 1;
  for (uint32_t i = blockIdx.x * 256 + threadIdx.x; i < cnt;
       i += gridDim.x * 256) {
    uint32_t n = ws[LIST_WS + i];
    RejConst rc = make_rej(1.0f / img[n]);
    uint32_t p = n;
    int t = 0, j = 0;
    while (t < T_WIN) {
      float kf;
      bool acc = rej_step_tab(rc, rj4[j], p, lgtab, kf);
      if (acc) {
        uint32_t fa = (uint32_t)(j + 1);
        if (fa > mymax) mymax = fa;
        ++t; p += N_PIX; j = 0;
      } else if (++j >= RJ_MAX) {
        mymax = RJ_MAX;
        ++t; p += N_PIX; j = 0;
      }
    }
  }
  // wave-reduce max, one atomic per wave
  for (int s = 32; s > 0; s >>= 1) {
    uint32_t o = (uint32_t)__shfl_xor((int)mymax, s, 64);
    if (o > mymax) mymax = o;
  }
  if ((threadIdx.x & 63) == 0) atomicMax((unsigned int*)gmax, mymax);
}

// ---------------- pass 1: masked survivors from bitmap, j>=1 -----------------
__global__ void __launch_bounds__(256)
pass1(uint32_t* __restrict__ ws, uint32_t* __restrict__ gmax) {
  __shared__ uint4 rj4[RJ_MAX];
  __shared__ float lgtab[TAB_N];
  for (int i = threadIdx.x; i < RJ_MAX; i += 256) {
    uint32_t b = KN_MAX * 2 + 4 * i;
    rj4[i] = make_uint4(ws[b], ws[b + 1], ws[b + 2], ws[b + 3]);
  }
  for (int i = threadIdx.x; i < TAB_N; i += 256)
    lgtab[i] = __uint_as_float(ws[TAB_WS + i]);
  __syncthreads();

  RejConst rc = load_mrc(ws);   // all masked-class survivors share this
  const unsigned long long* bm = (const unsigned long long*)(ws + BM_WS);
  uint32_t idx = blockIdx.x * 256 + threadIdx.x;   // one word per lane
  uint32_t mymax = 1;
  if (idx < (uint32_t)N_WORDS) {
    unsigned long long m = bm[idx];
    uint32_t waveGlobal = idx / T_WIN;
    uint32_t t = idx - waveGlobal * T_WIN;
    uint32_t nbase = waveGlobal * 64u;
    uint32_t pbase = t * (uint32_t)N_PIX + nbase;
    while (m) {
      int b = __builtin_ctzll(m);
      m &= (m - 1);
      uint32_t p = pbase + (uint32_t)b;
      uint32_t fa = RJ_MAX;
      for (int j = 1; j < RJ_MAX; ++j) {
        float kf;
        if (rej_step_tab(rc, rj4[j], p, lgtab, kf)) { fa = (uint32_t)(j + 1); break; }
      }
      if (fa > mymax) mymax = fa;
    }
  }
  for (int s = 32; s > 0; s >>= 1) {
    uint32_t o = (uint32_t)__shfl_xor((int)mymax, s, 64);
    if (o > mymax) mymax = o;
  }
  if ((threadIdx.x & 63) == 0) atomicMax((unsigned int*)gmax, mymax);
}

// ---------------- fallback: full first-accept scan (r7 gmax) -----------------
__global__ void __launch_bounds__(512)
rej_gmax_full(const float* __restrict__ img, const uint32_t* __restrict__ ws,
              uint32_t* __restrict__ gmax, int use_table) {
  __shared__ uint4 rj4[RJ_MAX];
  __shared__ float lgtab[TAB_N];
  __shared__ int waveRej[8];
  __shared__ unsigned short order[512];
  __shared__ uint32_t red[512];

  const int tid = threadIdx.x;
  for (int i = tid; i < RJ_MAX; i += 512) {
    uint32_t b = KN_MAX * 2 + 4 * i;
    rj4[i] = make_uint4(ws[b], ws[b + 1], ws[b + 2], ws[b + 3]);
  }
  if (use_table)
    for (int i = tid; i < TAB_N; i += 512) lgtab[i] = __uint_as_float(ws[TAB_WS + i]);

  int n0 = blockIdx.x * 512 + tid;
  float uimg0 = img[n0];
  bool isRej = (uimg0 != 0.0f) && !((1.0f / uimg0) < 10.0f);
  int lane = tid & 63, w = tid >> 6;
  unsigned long long bal = __ballot(isRej ? 1 : 0);
  int within = (int)__popcll(bal & ((1ull << lane) - 1ull));
  if (lane == 0) waveRej[w] = (int)__popcll(bal);
  __syncthreads();
  int rejBefore = 0, totalRej = 0;
  for (int i = 0; i < 8; ++i) { int c = waveRej[i]; totalRej += c; if (i < w) rejBefore += c; }
  int nMasked = 512 - totalRej;
  int slot = isRej ? (nMasked + rejBefore + within)
                   : (64 * w - rejBefore) + (lane - within);
  order[slot] = (unsigned short)tid;
  __syncthreads();

  int n = blockIdx.x * 512 + (int)order[tid];
  bool myRej = (tid >= nMasked);
  RejConst rc = make_rej(myRej ? (1.0f / img[n]) : 100000.0f);

  uint32_t mymax = 1;
  {
    uint32_t p = (uint32_t)n;
    int t = 0, j = 0;
    while (t < T_WIN) {
      float kf;
      bool acc;
      if (use_table) acc = rej_step_tab(rc, rj4[j], p, lgtab, kf);
      else           acc = rej_step4(rc, rj4[j], p, kf);
      if (acc) {
        uint32_t fa = (uint32_t)(j + 1);
        if (fa > mymax) mymax = fa;
        ++t; p += N_PIX; j = 0;
      } else if (++j >= RJ_MAX) {
        mymax = RJ_MAX;
        ++t; p += N_PIX; j = 0;
      }
    }
  }
  red[tid] = mymax;
  __syncthreads();
  for (int s2 = 256; s2 > 0; s2 >>= 1) {
    if (tid < s2) {
      uint32_t o = red[tid + s2];
      if (o > red[tid]) red[tid] = o;
    }
    __syncthreads();
  }
  if (tid == 0) atomicMax((unsigned int*)gmax, red[0]);
}

// ---------------- pass 2: one thread per pixel, compacted + flattened --------
__global__ void __launch_bounds__(512)
spike_main(const float* __restrict__ img, int* __restrict__ out,
           const uint32_t* __restrict__ chains) {
  __shared__ uint2 kn2[KN_MAX];
  __shared__ uint4 rj4[RJ_MAX];
  __shared__ int waveRej[8];
  __shared__ unsigned short order[512];
  __shared__ int shG;
  __shared__ ulonglong2 bmsh[512];

  const int tid = threadIdx.x;
  for (int i = tid; i < KN_MAX; i += 512)
    kn2[i] = make_uint2(chains[2 * i], chains[2 * i + 1]);
  for (int i = tid; i < RJ_MAX; i += 512) {
    uint32_t b = KN_MAX * 2 + 4 * i;
    rj4[i] = make_uint4(chains[b], chains[b + 1], chains[b + 2], chains[b + 3]);
  }
  if (tid == 0) shG = (int)chains[G_SLOT];

  int n0 = blockIdx.x * 512 + tid;
  float uimg0 = img[n0];
  bool isRej = (uimg0 != 0.0f) && !((1.0f / uimg0) < 10.0f);
  int lane = tid & 63, w = tid >> 6;
  unsigned long long bal = __ballot(isRej ? 1 : 0);
  int within = (int)__popcll(bal & ((1ull << lane) - 1ull));
  if (lane == 0) waveRej[w] = (int)__popcll(bal);
  __syncthreads();
  int rejBefore = 0, totalRej = 0;
  for (int i = 0; i < 8; ++i) { int c = waveRej[i]; totalRej += c; if (i < w) rejBefore += c; }
  int nMasked = 512 - totalRej;
  int slot = isRej ? (nMasked + rejBefore + within)
                   : (64 * w - rejBefore) + (lane - within);
  order[slot] = (unsigned short)tid;
  __syncthreads();

  const int G = shG;
  int nl = (int)order[tid];
  int n = blockIdx.x * 512 + nl;
  bool myRej = (tid >= nMasked);
  float uimg = img[n];
  unsigned long long bm0 = 0ull, bm1 = 0ull;  // spike bitmap: bit (s-1), s in [1,100]

  if (myRej) {
    // Rejection: last accept in [0,G) == first accept scanning DOWN
    RejConst rc = make_rej(1.0f / uimg);
    uint32_t p = (uint32_t)n;
    int s = 0, j = G - 1, t = 0;
    while (t < T_WIN) {
      float kf;
      bool acc = rej_step4(rc, rj4[j], p, kf);
      if (acc) {
        int iv = (kf >= 102.0f) ? 102 : (int)kf;  // values >100 all dead
        if (iv == 0) iv = 1;
        s += iv;
        if (s > T_WIN) break;
        if (s <= 64) bm0 |= 1ull << (s - 1); else bm1 |= 1ull << (s - 65);
        ++t; p += N_PIX; j = G - 1;
      } else if (--j < 0) {
        break;  // impossible: G covers every position's first accept
      }
    }
  } else if (uimg != 0.0f) {
    // Knuth, flattened: one draw per step, per-lane (t,j,k,lp,s)
    float lam = 1.0f / uimg;
    float neg_lam = -lam;
    uint32_t p = (uint32_t)n;
    int s = 0, k = 0, j = 0;
    float lp = 0.0f;
    while (true) {
      uint2 sk = kn2[j];
      float u = bits_to_unit(unif_bits(sk.x, sk.y, p));
      ++k; ++j;
      lp = lp + xla_logf(u);
      if (lp <= neg_lam || j >= KN_MAX) {   // this t resolved
        int iv = k - 1;
        if (iv == 0) iv = 1;                // nz & interval==0 -> 1
        s += iv;
        if (s > T_WIN) break;               // integer cumsum <=100 exact
        if (s <= 64) bm0 |= 1ull << (s - 1); else bm1 |= 1ull << (s - 65);
        p += N_PIX; j = 0; k = 0; lp = 0.0f;
        if (p >= (uint32_t)T_WIN * (uint32_t)N_PIX) break;
      }
    }
  }

  // Stage bitmaps in LDS, write columns in ORIGINAL pixel order (coalesced).
  ulonglong2 bm; bm.x = bm0; bm.y = bm1;
  bmsh[nl] = bm;
  __syncthreads();
  ulonglong2 b2 = bmsh[tid];
  size_t base = (size_t)(blockIdx.x * 512 + tid);
  for (int t = 0; t < 64; ++t)
    out[base + (size_t)t * N_PIX] = (int)((b2.x >> t) & 1ull);
  for (int t = 64; t < T_WIN; ++t)
    out[base + (size_t)t * N_PIX] = (int)((b2.y >> (t - 64)) & 1ull);
}

extern "C" void kernel_launch(void* const* d_in, const int* in_sizes, int n_in,
                              void* d_out, int out_size, void* d_ws, size_t ws_size,
                              hipStream_t stream) {
  const float* img = (const float*)d_in[0];
  int* out = (int*)d_out;
  uint32_t* ws = (uint32_t*)d_ws;
  int use_table = (ws_size >= WS_TAB_NEEDED) ? 1 : 0;
  int use_fast  = (use_table && ws_size >= WS_FAST_NEEDED) ? 1 : 0;

  hipLaunchKernelGGL(chain_init, dim3(2 + TAB_N / 256), dim3(256), 0, stream,
                     ws, use_table, use_fast);
  if (use_fast) {
    hipLaunchKernelGGL(pass0_masked, dim3(N_PIX / 256), dim3(256), 0, stream,
                       img, ws);
    hipLaunchKernelGGL(pass0R, dim3(320), dim3(256), 0, stream,
                       img, ws, ws + G_SLOT);
    hipLaunchKernelGGL(pass1, dim3(N_WORDS / 256), dim3(256), 0, stream,
                       ws, ws + G_SLOT);
  } else {
    hipLaunchKernelGGL(rej_gmax_full, dim3(N_PIX / 512), dim3(512), 0, stream,
                       img, ws, ws + G_SLOT, use_table);
  }
  hipLaunchKernelGGL(spike_main, dim3(N_PIX / 512), dim3(512), 0, stream,
                     img, out, ws);
}

// Round 10
// 1737.960 us; speedup vs baseline: 1.4760x; 1.0345x over previous
//
#include <hip/hip_runtime.h>
#include <math.h>
#include <stdint.h>

// Keep compiler contraction OFF globally: the ONLY fusions are my explicit
// fmaf() calls, which model LLVM's contract-FMF fusion on the XLA CPU host.
#pragma clang fp contract(off)

#define N_PIX 802816          // 16*1*224*224 = 512*1568
#define T_WIN 100
#define KN_MAX 96             // Knuth subkey chain length
#define RJ_MAX 48             // rejection subkey chain length (G ~ 10)
#define N_WAVES (N_PIX / 64)  // 12544
#define N_WORDS (N_WAVES * T_WIN)  // 1254400 bitmap words

#define G_SLOT 384            // = KN_MAX*2 + RJ_MAX*4
#define MRC_WS  385           // 8 floats: make_rej(1e5) fields
#define CNT_WS  393           // rejection-pixel list count
#define TAB_WS  394
#define TAB_BASE 98000
#define TAB_N    4096
#define LIST_WS (TAB_WS + TAB_N)          // cap N_PIX entries -> no overflow
#define BM_WS   (LIST_WS + N_PIX)         // even -> 8B aligned
#define WS_TAB_NEEDED ((size_t)(TAB_WS + TAB_N) * 4)
#define WS_FAST_NEEDED ((size_t)(BM_WS + 2 * N_WORDS) * 4)   // ~13.3 MB
#define WPB 16                // bitmap words per passA block (1024 positions)

// ---------------- threefry2x32 (JAX rotation/injection schedule) -------------
__device__ __forceinline__ void tf2x32(uint32_t k0, uint32_t k1,
                                       uint32_t x0, uint32_t x1,
                                       uint32_t &o0, uint32_t &o1) {
  uint32_t ks2 = k0 ^ k1 ^ 0x1BD11BDAu;
  x0 += k0; x1 += k1;
#define TF_R(r) { x0 += x1; x1 = (x1 << (r)) | (x1 >> (32 - (r))); x1 ^= x0; }
  TF_R(13) TF_R(15) TF_R(26) TF_R(6)
  x0 += k1;  x1 += ks2 + 1u;
  TF_R(17) TF_R(29) TF_R(16) TF_R(24)
  x0 += ks2; x1 += k0 + 2u;
  TF_R(13) TF_R(15) TF_R(26) TF_R(6)
  x0 += k0;  x1 += k1 + 3u;
  TF_R(17) TF_R(29) TF_R(16) TF_R(24)
  x0 += k1;  x1 += ks2 + 4u;
  TF_R(13) TF_R(15) TF_R(26) TF_R(6)
  x0 += ks2; x1 += k0 + 5u;
#undef TF_R
  o0 = x0; o1 = x1;
}

__device__ __forceinline__ uint32_t unif_bits(uint32_t s0, uint32_t s1, uint32_t p) {
  uint32_t a, b;
  tf2x32(s0, s1, 0u, p, a, b);
  return a ^ b;
}

__device__ __forceinline__ float bits_to_unit(uint32_t bits) {
  return __uint_as_float(0x3f800000u | (bits >> 9)) - 1.0f;
}

// ---------------- XLA CPU f32 log (verified bit-exact in round 5) ------------
__device__ __forceinline__ float xla_logf(float xin) {
#pragma clang fp contract(off)
  if (xin == 0.0f) return __uint_as_float(0xff800000u);           // -inf
  if (!(xin > 0.0f)) return __uint_as_float(0x7fc00000u);         // nan
  float x = fmaxf(xin, __uint_as_float(0x00800000u));             // flush denorm
  uint32_t ib = __float_as_uint(x);
  float e = (float)((int)(ib >> 23) - 126);
  ib = (ib & 0x007fffffu) | 0x3f000000u;                          // [0.5,1)
  x = __uint_as_float(ib);
  float tmp = 0.0f, eadj = 0.0f;
  if (x < (float)0.707106781186547524) { tmp = x; eadj = 1.0f; }
  x = x - 1.0f;
  e = e - eadj;
  x = x + tmp;
  float x2 = x * x;
  float x3 = x2 * x;
  float y  = fmaf((float)7.0376836292e-2,  x, (float)-1.1514610310e-1);
  float y1 = fmaf((float)-1.2420140846e-1, x, (float)1.4249322787e-1);
  float y2 = fmaf((float)2.0000714765e-1,  x, (float)-2.4999993993e-1);
  y  = fmaf(y,  x, (float)1.1676998740e-1);
  y1 = fmaf(y1, x, (float)-1.6668057665e-1);
  y2 = fmaf(y2, x, (float)3.3333331174e-1);
  y  = fmaf(y, x3, y1);
  y  = fmaf(y, x3, y2);
  float eq1 = e * (float)-2.12194440e-4;   // standalone mul
  y = fmaf(y, x3, eq1);                    // fadd(mul,mul): operand-0 fuses
  x = fmaf(-x2, 0.5f, x);                  // fsub(x, mul) -> fnmadd
  x = x + y;                               // add of two fma results
  x = fmaf(e, (float)0.693359375, x);      // fadd(x, mul) -> fma
  return x;
}

__device__ __forceinline__ float xla_log1pf(float w) {
#pragma clang fp contract(off)
  if (fabsf(w) < (float)1e-4) return fmaf(-0.5f, w, 1.0f) * w;
  return xla_logf(w + 1.0f);
}

__device__ __forceinline__ float xla_lgammaf_pos(float x) {
#pragma clang fp contract(off)
  const float kBase = (float)0.99999999999980993227684700473478;
  const float c0 = (float)676.520368121885098567009190444019;
  const float c1 = (float)-1259.13921672240287047156078755283;
  const float c2 = (float)771.3234287776530788486528258894;
  const float c3 = (float)-176.61502916214059906584551354;
  const float c4 = (float)12.507343278686904814458936853;
  const float c5 = (float)-0.13857109526572011689554707;
  const float c6 = (float)9.984369578019570859563e-6;
  const float c7 = (float)1.50563273514931155834e-7;
  const float kLogSqrtTwoPi = (float)0.91893853320467274178032973640562;
  const float kGPlusHalf = 7.5f;
  const float kLogGPlusHalf = (float)2.0149030205422647065; // log(7.5)
  float z = x - 1.0f;
  float sum = kBase;
  sum = sum + c0 / ((z + 0.0f) + 1.0f);
  sum = sum + c1 / ((z + 1.0f) + 1.0f);
  sum = sum + c2 / ((z + 2.0f) + 1.0f);
  sum = sum + c3 / ((z + 3.0f) + 1.0f);
  sum = sum + c4 / ((z + 4.0f) + 1.0f);
  sum = sum + c5 / ((z + 5.0f) + 1.0f);
  sum = sum + c6 / ((z + 6.0f) + 1.0f);
  sum = sum + c7 / ((z + 7.0f) + 1.0f);
  float t = kGPlusHalf + z;
  float log_t = kLogGPlusHalf + xla_log1pf(z / kGPlusHalf);
  float log_y = fmaf((z + 0.5f) - t / log_t, log_t, kLogSqrtTwoPi) + xla_logf(sum);
  return log_y;
}

// ---------------- rejection sampler shared pieces ----------------------------
struct RejConst {
  float lam, neg_lam, log_lam, aa, bb, inv_alpha, v_r, two_a;
};

__device__ __forceinline__ RejConst make_rej(float lam) {
  RejConst rc;
  rc.lam = lam;
  rc.neg_lam = -lam;
  rc.log_lam = xla_logf(lam);
  float sq = (float)sqrt((double)lam);                  // CR f32 sqrt
  rc.bb = fmaf(2.53f, sq, (float)0.931);
  rc.aa = fmaf((float)0.02483, rc.bb, (float)-0.059);
  rc.inv_alpha = (float)1.1239 + (float)1.1328 / (rc.bb - (float)3.4);
  rc.v_r = (float)0.9277 - (float)3.6224 / (rc.bb - 2.0f);
  rc.two_a = 2.0f * rc.aa;
  return rc;
}

// One rejection iteration (full lgamma) -- byte-identical to rounds 5-9.
__device__ __forceinline__ bool rej_step4(const RejConst& rc, uint4 ch,
                                          uint32_t p, float& kf_out) {
  float u = bits_to_unit(unif_bits(ch.x, ch.y, p)) - 0.5f;
  float v = bits_to_unit(unif_bits(ch.z, ch.w, p));
  float u_sh = 0.5f - fabsf(u);
  float kf = floorf(fmaf(rc.two_a / u_sh + rc.bb, u, rc.lam) + (float)0.43);
  kf_out = kf;
  if ((u_sh >= (float)0.07) && (v <= rc.v_r)) return true;          // accept1
  if ((kf < 0.0f) || ((u_sh < (float)0.013) && (v > u_sh))) return false; // reject
  float sv = xla_logf((v * rc.inv_alpha) / ((rc.aa / (u_sh * u_sh)) + rc.bb));
  float tv = fmaf(kf, rc.log_lam, rc.neg_lam) - xla_lgammaf_pos(kf + 1.0f);
  return sv <= tv;                                                  // accept2
}

// Table-assisted via GLOBAL table read (L2); identical bits (table = fn(kf)).
__device__ __forceinline__ bool rej_step_tab_g(const RejConst& rc, uint4 ch,
                                               uint32_t p,
                                               const uint32_t* __restrict__ ws,
                                               float& kf_out) {
  float u = bits_to_unit(unif_bits(ch.x, ch.y, p)) - 0.5f;
  float v = bits_to_unit(unif_bits(ch.z, ch.w, p));
  float u_sh = 0.5f - fabsf(u);
  float kf = floorf(fmaf(rc.two_a / u_sh + rc.bb, u, rc.lam) + (float)0.43);
  kf_out = kf;
  if ((u_sh >= (float)0.07) && (v <= rc.v_r)) return true;          // accept1
  if ((kf < 0.0f) || ((u_sh < (float)0.013) && (v > u_sh))) return false; // reject
  float sv = xla_logf((v * rc.inv_alpha) / ((rc.aa / (u_sh * u_sh)) + rc.bb));
  int ki = (int)kf - TAB_BASE;
  float lg = (ki >= 0 && ki < TAB_N) ? __uint_as_float(ws[TAB_WS + ki])
                                     : xla_lgammaf_pos(kf + 1.0f);
  float tv = fmaf(kf, rc.log_lam, rc.neg_lam) - lg;
  return sv <= tv;                                                  // accept2
}

__device__ __forceinline__ RejConst load_mrc(const uint32_t* __restrict__ ws) {
  RejConst rc;
  rc.lam       = __uint_as_float(ws[MRC_WS + 0]);
  rc.neg_lam   = __uint_as_float(ws[MRC_WS + 1]);
  rc.log_lam   = __uint_as_float(ws[MRC_WS + 2]);
  rc.aa        = __uint_as_float(ws[MRC_WS + 3]);
  rc.bb        = __uint_as_float(ws[MRC_WS + 4]);
  rc.inv_alpha = __uint_as_float(ws[MRC_WS + 5]);
  rc.v_r       = __uint_as_float(ws[MRC_WS + 6]);
  rc.two_a     = __uint_as_float(ws[MRC_WS + 7]);
  return rc;
}

// guarded atomic: gmax grows monotonically; skip no-op atomics
__device__ __forceinline__ void gmax_update(uint32_t* gmax, uint32_t v) {
  if (v > *((volatile unsigned int*)gmax)) atomicMax((unsigned int*)gmax, v);
}

// ---------------- prologue: chains + mrc + lgamma table ----------------------
__global__ void chain_init(uint32_t* __restrict__ ws, int build_table, int fast) {
  if (blockIdx.x == 0) {
    if (threadIdx.x != 0) return;
    ws[G_SLOT] = 1u;                       // G >= 1 always
    if (fast) ws[CNT_WS] = 0u;
    uint32_t r0 = 0u, r1 = 42u;            // jax.random.key(42) -> (0,42)
    for (int j = 0; j < KN_MAX; ++j) {
      uint32_t s0, s1, n0, n1;
      tf2x32(r0, r1, 0u, 1u, s0, s1);
      tf2x32(r0, r1, 0u, 0u, n0, n1);
      ws[2 * j] = s0; ws[2 * j + 1] = s1;
      r0 = n0; r1 = n1;
    }
  } else if (blockIdx.x == 1) {
    if (threadIdx.x == 0) {
      uint32_t c0 = 0u, c1 = 42u;
      for (int j = 0; j < RJ_MAX; ++j) {
        uint32_t a0, a1, b0, b1, n0, n1;
        tf2x32(c0, c1, 0u, 1u, a0, a1);
        tf2x32(c0, c1, 0u, 2u, b0, b1);
        tf2x32(c0, c1, 0u, 0u, n0, n1);
        uint32_t base = KN_MAX * 2 + 4 * j;
        ws[base + 0] = a0; ws[base + 1] = a1; ws[base + 2] = b0; ws[base + 3] = b1;
        c0 = n0; c1 = n1;
      }
    } else if (threadIdx.x == 64) {
      RejConst m = make_rej(100000.0f);
      ws[MRC_WS + 0] = __float_as_uint(m.lam);
      ws[MRC_WS + 1] = __float_as_uint(m.neg_lam);
      ws[MRC_WS + 2] = __float_as_uint(m.log_lam);
      ws[MRC_WS + 3] = __float_as_uint(m.aa);
      ws[MRC_WS + 4] = __float_as_uint(m.bb);
      ws[MRC_WS + 5] = __float_as_uint(m.inv_alpha);
      ws[MRC_WS + 6] = __float_as_uint(m.v_r);
      ws[MRC_WS + 7] = __float_as_uint(m.two_a);
    }
  } else if (build_table) {
    int i = (blockIdx.x - 2) * 256 + threadIdx.x;   // 16 blocks x 256 = TAB_N
    if (i < TAB_N) {
      float kf = (float)(TAB_BASE + i);             // exact (< 2^24)
      ws[TAB_WS + i] = __float_as_uint(xla_lgammaf_pos(kf + 1.0f));
    }
  }
}

// ---------------- pass 0: ACCEPT1-ONLY j=0 scan for all pixels ---------------
// Per step: 2 hashes + u_sh/v_r compare. No kf, no divides, no accept2, no LDS.
// Bitmap bit = "failed accept1 at j=0" (masked-class pixels only).
__global__ void __launch_bounds__(256)
pass0_masked(const float* __restrict__ img, uint32_t* __restrict__ ws) {
  const int tid = threadIdx.x;
  const int lane = tid & 63, w = tid >> 6;
  int n = blockIdx.x * 256 + tid;
  float uimg = img[n];
  bool isRej = (uimg != 0.0f) && !((1.0f / uimg) < 10.0f);

  // append rejection-class pixels to list (wave-aggregated, order-free)
  {
    unsigned long long bal = __ballot(isRej ? 1 : 0);
    if (bal) {
      uint32_t cntw = (uint32_t)__popcll(bal);
      uint32_t base = 0;
      if (lane == 0) base = atomicAdd(ws + CNT_WS, cntw);
      base = (uint32_t)__shfl((int)base, 0, 64);
      if (isRej) {
        uint32_t rank = (uint32_t)__popcll(bal & ((1ull << lane) - 1ull));
        ws[LIST_WS + base + rank] = (uint32_t)n;
      }
    }
  }

  float v_r = __uint_as_float(ws[MRC_WS + 6]);     // uniform (SGPR)
  uint4 ch0 = make_uint4(ws[KN_MAX * 2 + 0], ws[KN_MAX * 2 + 1],
                         ws[KN_MAX * 2 + 2], ws[KN_MAX * 2 + 3]);
  unsigned long long* bm = (unsigned long long*)(ws + BM_WS);
  const uint32_t waveGlobal = (uint32_t)(blockIdx.x * 4 + w);
  uint32_t p = (uint32_t)n;
  for (int t = 0; t < T_WIN; ++t, p += N_PIX) {
    float u = bits_to_unit(unif_bits(ch0.x, ch0.y, p)) - 0.5f;
    float v = bits_to_unit(unif_bits(ch0.z, ch0.w, p));
    float u_sh = 0.5f - fabsf(u);
    bool notAcc1 = !((u_sh >= (float)0.07) && (v <= v_r));
    unsigned long long mask = __ballot((notAcc1 && !isRej) ? 1 : 0);
    if (lane == 0) bm[waveGlobal * T_WIN + t] = mask;
  }
}

// ---------------- pass A: resolve accept1-failures; j-scan survivors ---------
__global__ void __launch_bounds__(256)
passA(uint32_t* __restrict__ ws, uint32_t* __restrict__ gmax) {
  __shared__ uint4 rj4[RJ_MAX];
  __shared__ uint32_t q1[WPB * 64];
  __shared__ uint32_t q2[WPB * 64];
  __shared__ uint32_t q1n, q2n, q2c;
  const int tid = threadIdx.x;
  for (int i = tid; i < RJ_MAX; i += 256) {
    uint32_t b = KN_MAX * 2 + 4 * i;
    rj4[i] = make_uint4(ws[b], ws[b + 1], ws[b + 2], ws[b + 3]);
  }
  if (tid == 0) { q1n = 0u; q2n = 0u; q2c = 0u; }
  __syncthreads();

  // enumerate set bits of my 16 bitmap words into q1 (order-free: max-reduce)
  const unsigned long long* bm = (const unsigned long long*)(ws + BM_WS);
  uint32_t w0 = (uint32_t)blockIdx.x * WPB;
  for (int s = tid; s < WPB * 64; s += 256) {
    uint32_t wi = w0 + (uint32_t)(s >> 6);
    unsigned long long word = bm[wi];
    uint32_t bit = (uint32_t)(s & 63);
    if ((word >> bit) & 1ull) {
      uint32_t wave = wi / (uint32_t)T_WIN;
      uint32_t t = wi - wave * (uint32_t)T_WIN;
      uint32_t p = t * (uint32_t)N_PIX + wave * 64u + bit;
      uint32_t qi = atomicAdd(&q1n, 1u);
      q1[qi] = p;
    }
  }
  __syncthreads();

  RejConst rc = load_mrc(ws);
  uint4 ch0 = rj4[0];
  uint32_t mymax = 1;
  uint32_t n1 = q1n;

  // phase 1: resolve j=0 for entries known to fail accept1
  for (uint32_t qi = tid; qi < n1; qi += 256) {
    uint32_t p = q1[qi];
    float u = bits_to_unit(unif_bits(ch0.x, ch0.y, p)) - 0.5f;
    float v = bits_to_unit(unif_bits(ch0.z, ch0.w, p));
    float u_sh = 0.5f - fabsf(u);
    float kf = floorf(fmaf(rc.two_a / u_sh + rc.bb, u, rc.lam) + (float)0.43);
    bool rejected;
    if ((kf < 0.0f) || ((u_sh < (float)0.013) && (v > u_sh))) {
      rejected = true;
    } else {
      float sv = xla_logf((v * rc.inv_alpha) / ((rc.aa / (u_sh * u_sh)) + rc.bb));
      int ki = (int)kf - TAB_BASE;
      float lg = (ki >= 0 && ki < TAB_N) ? __uint_as_float(ws[TAB_WS + ki])
                                         : xla_lgammaf_pos(kf + 1.0f);
      float tv = fmaf(kf, rc.log_lam, rc.neg_lam) - lg;
      rejected = !(sv <= tv);
    }
    if (rejected) { uint32_t q = atomicAdd(&q2n, 1u); q2[q] = p; }
  }
  __syncthreads();

  // phase 2: persistent-lane first-accept scan from j=1 (dense)
  uint32_t n2 = q2n;
  {
    uint32_t p = 0; int j = 0;
    bool have = false, exhausted = (n2 == 0);
    while (!__all((!have) && exhausted)) {
      if (!have && !exhausted) {
        uint32_t qi = atomicAdd(&q2c, 1u);
        if (qi < n2) { p = q2[qi]; j = 1; have = true; }
        else exhausted = true;
      }
      if (have) {
        float kf;
        bool acc = rej_step_tab_g(rc, rj4[j], p, ws, kf);
        if (acc) {
          uint32_t fa = (uint32_t)(j + 1);
          if (fa > mymax) mymax = fa;
          have = false;
        } else if (++j >= RJ_MAX) {
          if ((uint32_t)RJ_MAX > mymax) mymax = RJ_MAX;
          have = false;
        }
      }
    }
  }
  for (int s = 32; s > 0; s >>= 1) {
    uint32_t o = (uint32_t)__shfl_xor((int)mymax, s, 64);
    if (o > mymax) mymax = o;
  }
  if ((tid & 63) == 0) gmax_update(gmax, mymax);
}

// ---------------- pass 0R: rejection-class pixels, dense automaton -----------
__global__ void __launch_bounds__(256)
pass0R(const float* __restrict__ img, uint32_t* __restrict__ ws,
       uint32_t* __restrict__ gmax) {
  __shared__ uint4 rj4[RJ_MAX];
  for (int i = threadIdx.x; i < RJ_MAX; i += 256) {
    uint32_t b = KN_MAX * 2 + 4 * i;
    rj4[i] = make_uint4(ws[b], ws[b + 1], ws[b + 2], ws[b + 3]);
  }
  __syncthreads();

  uint32_t cnt = ws[CNT_WS];
  uint32_t mymax = 1;
  for (uint32_t i = blockIdx.x * 256 + threadIdx.x; i < cnt;
       i += gridDim.x * 256) {
    uint32_t n = ws[LIST_WS + i];
    RejConst rc = make_rej(1.0f / img[n]);
    uint32_t p = n;
    int t = 0, j = 0;
    while (t < T_WIN) {
      float kf;
      bool acc = rej_step4(rc, rj4[j], p, kf);
      if (acc) {
        uint32_t fa = (uint32_t)(j + 1);
        if (fa > mymax) mymax = fa;
        ++t; p += N_PIX; j = 0;
      } else if (++j >= RJ_MAX) {
        mymax = RJ_MAX;
        ++t; p += N_PIX; j = 0;
      }
    }
  }
  for (int s = 32; s > 0; s >>= 1) {
    uint32_t o = (uint32_t)__shfl_xor((int)mymax, s, 64);
    if (o > mymax) mymax = o;
  }
  if ((threadIdx.x & 63) == 0) gmax_update(gmax, mymax);
}

// ---------------- fallback: full first-accept scan (r7 gmax) -----------------
__global__ void __launch_bounds__(512)
rej_gmax_full(const float* __restrict__ img, const uint32_t* __restrict__ ws,
              uint32_t* __restrict__ gmax, int use_table) {
  __shared__ uint4 rj4[RJ_MAX];
  __shared__ int waveRej[8];
  __shared__ unsigned short order[512];
  __shared__ uint32_t red[512];

  const int tid = threadIdx.x;
  for (int i = tid; i < RJ_MAX; i += 512) {
    uint32_t b = KN_MAX * 2 + 4 * i;
    rj4[i] = make_uint4(ws[b], ws[b + 1], ws[b + 2], ws[b + 3]);
  }

  int n0 = blockIdx.x * 512 + tid;
  float uimg0 = img[n0];
  bool isRej = (uimg0 != 0.0f) && !((1.0f / uimg0) < 10.0f);
  int lane = tid & 63, w = tid >> 6;
  unsigned long long bal = __ballot(isRej ? 1 : 0);
  int within = (int)__popcll(bal & ((1ull << lane) - 1ull));
  if (lane == 0) waveRej[w] = (int)__popcll(bal);
  __syncthreads();
  int rejBefore = 0, totalRej = 0;
  for (int i = 0; i < 8; ++i) { int c = waveRej[i]; totalRej += c; if (i < w) rejBefore += c; }
  int nMasked = 512 - totalRej;
  int slot = isRej ? (nMasked + rejBefore + within)
                   : (64 * w - rejBefore) + (lane - within);
  order[slot] = (unsigned short)tid;
  __syncthreads();

  int n = blockIdx.x * 512 + (int)order[tid];
  bool myRej = (tid >= nMasked);
  RejConst rc = make_rej(myRej ? (1.0f / img[n]) : 100000.0f);

  uint32_t mymax = 1;
  {
    uint32_t p = (uint32_t)n;
    int t = 0, j = 0;
    while (t < T_WIN) {
      float kf;
      bool acc;
      if (use_table) acc = rej_step_tab_g(rc, rj4[j], p, ws, kf);
      else           acc = rej_step4(rc, rj4[j], p, kf);
      if (acc) {
        uint32_t fa = (uint32_t)(j + 1);
        if (fa > mymax) mymax = fa;
        ++t; p += N_PIX; j = 0;
      } else if (++j >= RJ_MAX) {
        mymax = RJ_MAX;
        ++t; p += N_PIX; j = 0;
      }
    }
  }
  red[tid] = mymax;
  __syncthreads();
  for (int s2 = 256; s2 > 0; s2 >>= 1) {
    if (tid < s2) {
      uint32_t o = red[tid + s2];
      if (o > red[tid]) red[tid] = o;
    }
    __syncthreads();
  }
  if (tid == 0) atomicMax((unsigned int*)gmax, red[0]);
}

// ---------------- pass 2: one thread per pixel, compacted + flattened --------
__global__ void __launch_bounds__(512)
spike_main(const float* __restrict__ img, int* __restrict__ out,
           const uint32_t* __restrict__ chains) {
  __shared__ uint2 kn2[KN_MAX];
  __shared__ uint4 rj4[RJ_MAX];
  __shared__ int waveRej[8];
  __shared__ unsigned short order[512];
  __shared__ int shG;
  __shared__ ulonglong2 bmsh[512];

  const int tid = threadIdx.x;
  for (int i = tid; i < KN_MAX; i += 512)
    kn2[i] = make_uint2(chains[2 * i], chains[2 * i + 1]);
  for (int i = tid; i < RJ_MAX; i += 512) {
    uint32_t b = KN_MAX * 2 + 4 * i;
    rj4[i] = make_uint4(chains[b], chains[b + 1], chains[b + 2], chains[b + 3]);
  }
  if (tid == 0) shG = (int)chains[G_SLOT];

  int n0 = blockIdx.x * 512 + tid;
  float uimg0 = img[n0];
  bool isRej = (uimg0 != 0.0f) && !((1.0f / uimg0) < 10.0f);
  int lane = tid & 63, w = tid >> 6;
  unsigned long long bal = __ballot(isRej ? 1 : 0);
  int within = (int)__popcll(bal & ((1ull << lane) - 1ull));
  if (lane == 0) waveRej[w] = (int)__popcll(bal);
  __syncthreads();
  int rejBefore = 0, totalRej = 0;
  for (int i = 0; i < 8; ++i) { int c = waveRej[i]; totalRej += c; if (i < w) rejBefore += c; }
  int nMasked = 512 - totalRej;
  int slot = isRej ? (nMasked + rejBefore + within)
                   : (64 * w - rejBefore) + (lane - within);
  order[slot] = (unsigned short)tid;
  __syncthreads();

  const int G = shG;
  int nl = (int)order[tid];
  int n = blockIdx.x * 512 + nl;
  bool myRej = (tid >= nMasked);
  float uimg = img[n];
  unsigned long long bm0 = 0ull, bm1 = 0ull;  // spike bitmap: bit (s-1), s in [1,100]

  if (myRej) {
    // Rejection: last accept in [0,G) == first accept scanning DOWN
    RejConst rc = make_rej(1.0f / uimg);
    uint32_t p = (uint32_t)n;
    int s = 0, j = G - 1, t = 0;
    while (t < T_WIN) {
      float kf;
      bool acc = rej_step4(rc, rj4[j], p, kf);
      if (acc) {
        int iv = (kf >= 102.0f) ? 102 : (int)kf;  // values >100 all dead
        if (iv == 0) iv = 1;
        s += iv;
        if (s > T_WIN) break;
        if (s <= 64) bm0 |= 1ull << (s - 1); else bm1 |= 1ull << (s - 65);
        ++t; p += N_PIX; j = G - 1;
      } else if (--j < 0) {
        break;  // impossible: G covers every position's first accept
      }
    }
  } else if (uimg != 0.0f) {
    // Knuth, flattened: one draw per step, per-lane (t,j,k,lp,s)
    float lam = 1.0f / uimg;
    float neg_lam = -lam;
    uint32_t p = (uint32_t)n;
    int s = 0, k = 0, j = 0;
    float lp = 0.0f;
    while (true) {
      uint2 sk = kn2[j];
      float u = bits_to_unit(unif_bits(sk.x, sk.y, p));
      ++k; ++j;
      lp = lp + xla_logf(u);
      if (lp <= neg_lam || j >= KN_MAX) {   // this t resolved
        int iv = k - 1;
        if (iv == 0) iv = 1;                // nz & interval==0 -> 1
        s += iv;
        if (s > T_WIN) break;               // integer cumsum <=100 exact
        if (s <= 64) bm0 |= 1ull << (s - 1); else bm1 |= 1ull << (s - 65);
        p += N_PIX; j = 0; k = 0; lp = 0.0f;
        if (p >= (uint32_t)T_WIN * (uint32_t)N_PIX) break;
      }
    }
  }

  // Stage bitmaps in LDS, write columns in ORIGINAL pixel order (coalesced).
  ulonglong2 bm; bm.x = bm0; bm.y = bm1;
  bmsh[nl] = bm;
  __syncthreads();
  ulonglong2 b2 = bmsh[tid];
  size_t base = (size_t)(blockIdx.x * 512 + tid);
  for (int t = 0; t < 64; ++t)
    out[base + (size_t)t * N_PIX] = (int)((b2.x >> t) & 1ull);
  for (int t = 64; t < T_WIN; ++t)
    out[base + (size_t)t * N_PIX] = (int)((b2.y >> (t - 64)) & 1ull);
}

extern "C" void kernel_launch(void* const* d_in, const int* in_sizes, int n_in,
                              void* d_out, int out_size, void* d_ws, size_t ws_size,
                              hipStream_t stream) {
  const float* img = (const float*)d_in[0];
  int* out = (int*)d_out;
  uint32_t* ws = (uint32_t*)d_ws;
  int use_table = (ws_size >= WS_TAB_NEEDED) ? 1 : 0;
  int use_fast  = (use_table && ws_size >= WS_FAST_NEEDED) ? 1 : 0;

  hipLaunchKernelGGL(chain_init, dim3(2 + TAB_N / 256), dim3(256), 0, stream,
                     ws, use_table, use_fast);
  if (use_fast) {
    hipLaunchKernelGGL(pass0_masked, dim3(N_PIX / 256), dim3(256), 0, stream,
                       img, ws);
    hipLaunchKernelGGL(pass0R, dim3(320), dim3(256), 0, stream,
                       img, ws, ws + G_SLOT);
    hipLaunchKernelGGL(passA, dim3(N_WORDS / WPB), dim3(256), 0, stream,
                       ws, ws + G_SLOT);
  } else {
    hipLaunchKernelGGL(rej_gmax_full, dim3(N_PIX / 512), dim3(512), 0, stream,
                       img, ws, ws + G_SLOT, use_table);
  }
  hipLaunchKernelGGL(spike_main, dim3(N_PIX / 512), dim3(512), 0, stream,
                     img, out, ws);
}